// Round 11
// baseline (139.902 us; speedup 1.0000x reference)
//
#include <hip/hip_runtime.h>
#include <hip/hip_bf16.h>

#define S_LEN 1024
#define DMODEL 1024
#define N_HEADS 16
#define D_HEAD 64
#define BATCH 2
#define N_BH 32

typedef __attribute__((ext_vector_type(8))) short short8;
typedef __attribute__((ext_vector_type(4))) float f32x4;
typedef __attribute__((ext_vector_type(4))) int i32x4;

static __device__ __forceinline__ unsigned short f2bf(float x) {
    unsigned int u = __float_as_uint(x);
    return (unsigned short)((u + 0x7fffu + ((u >> 16) & 1u)) >> 16);
}

static __device__ __forceinline__ float bf2f(unsigned short h) {
    return __uint_as_float(((unsigned int)h) << 16);
}

static __device__ __forceinline__ float sum8(short8 v) {
    float s = 0.f;
#pragma unroll
    for (int j = 0; j < 8; ++j) s += bf2f((unsigned short)v[j]);
    return s;
}

// ---------------- one-time f32 -> bf16 conversion ----------------
// grid (2048, 7): z 0..3 = weights (1024^2), z 4..6 = inputs (2048x1024)
__global__ __launch_bounds__(256) void cvt_kernel(
    const float* __restrict__ wq, const float* __restrict__ wk,
    const float* __restrict__ wv, const float* __restrict__ wo,
    const float* __restrict__ q, const float* __restrict__ k,
    const float* __restrict__ v,
    unsigned short* __restrict__ Wb, unsigned short* __restrict__ Xb)
{
    const int z = blockIdx.y;
    const int idx = blockIdx.x * 256 + threadIdx.x;   // float4 index
    const float* src;
    unsigned short* dst;
    int n4;
    if (z < 4) {
        src = (z == 0) ? wq : (z == 1) ? wk : (z == 2) ? wv : wo;
        dst = Wb + (size_t)z * 1048576;
        n4 = 262144;
    } else {
        int j = z - 4;
        src = (j == 0) ? q : (j == 1) ? k : v;
        dst = Xb + (size_t)j * 2097152;
        n4 = 524288;
    }
    if (idx < n4) {
        f32x4 f = *reinterpret_cast<const f32x4*>(src + (size_t)idx * 4);
        ushort4 h = { f2bf(f[0]), f2bf(f[1]), f2bf(f[2]), f2bf(f[3]) };
        *reinterpret_cast<ushort4*>(dst + (size_t)idx * 4) = h;
    }
}

// ---------------- unified bf16 GEMM: C[n][j] = sum_d A[n][d]*W[j][d] + bias[j] ----------------
// BM=128, BN=128, BK=32. 256 thr = 4 waves (2x2), wave tile 64x64, frags 4x4.
// outmode 0: bf16 head-major; 1: bf16 V-transposed; 2: f32 flat
__device__ __forceinline__ void gemm_core(const unsigned short* __restrict__ A,
                                          const unsigned short* __restrict__ W,
                                          const float* __restrict__ bias,
                                          void* __restrict__ outp, int outmode,
                                          int n0, int j0)
{
    __shared__ unsigned short As[128 * 40];
    __shared__ unsigned short Bs[128 * 40];
    const int t = threadIdx.x;
    const int lane = t & 63, w = t >> 6;
    const int wm = w >> 1, wn = w & 1;
    const int g = lane >> 4, r = lane & 15;
    const int srow = t >> 2, seg = t & 3;   // staging: 64 rows/pass, 4 segs of 8

    f32x4 acc[4][4];
#pragma unroll
    for (int mi = 0; mi < 4; ++mi)
#pragma unroll
        for (int ni = 0; ni < 4; ++ni)
            acc[mi][ni] = (f32x4){0.f, 0.f, 0.f, 0.f};

    for (int ks = 0; ks < DMODEL / 32; ++ks) {
        const int k0 = ks * 32;
        __syncthreads();
#pragma unroll
        for (int i = 0; i < 2; ++i) {
            *reinterpret_cast<short8*>(&As[(srow + i * 64) * 40 + seg * 8]) =
                *reinterpret_cast<const short8*>(A + (size_t)(n0 + srow + i * 64) * DMODEL + k0 + seg * 8);
            *reinterpret_cast<short8*>(&Bs[(srow + i * 64) * 40 + seg * 8]) =
                *reinterpret_cast<const short8*>(W + (size_t)(j0 + srow + i * 64) * DMODEL + k0 + seg * 8);
        }
        __syncthreads();
        short8 af[4], bf[4];
#pragma unroll
        for (int mi = 0; mi < 4; ++mi)
            af[mi] = *reinterpret_cast<const short8*>(&As[(wm * 64 + mi * 16 + r) * 40 + g * 8]);
#pragma unroll
        for (int ni = 0; ni < 4; ++ni)
            bf[ni] = *reinterpret_cast<const short8*>(&Bs[(wn * 64 + ni * 16 + r) * 40 + g * 8]);
#pragma unroll
        for (int mi = 0; mi < 4; ++mi)
#pragma unroll
            for (int ni = 0; ni < 4; ++ni)
                acc[mi][ni] = __builtin_amdgcn_mfma_f32_16x16x32_bf16(af[mi], bf[ni], acc[mi][ni], 0, 0, 0);
    }

#pragma unroll
    for (int mi = 0; mi < 4; ++mi) {
#pragma unroll
        for (int ni = 0; ni < 4; ++ni) {
            int col = j0 + wn * 64 + ni * 16 + r;
            float bv = bias[col];
#pragma unroll
            for (int t4 = 0; t4 < 4; ++t4) {
                int n = n0 + wm * 64 + mi * 16 + g * 4 + t4;
                float v = acc[mi][ni][t4] + bv;
                if (outmode == 2) {
                    ((float*)outp)[(size_t)n * DMODEL + col] = v;
                } else {
                    int b_ = n >> 10, s_ = n & 1023;
                    int h_ = col >> 6, dh = col & 63;
                    if (outmode == 0)
                        ((unsigned short*)outp)[((size_t)(b_ * N_HEADS + h_) * S_LEN + s_) * D_HEAD + dh] = f2bf(v);
                    else
                        ((unsigned short*)outp)[((size_t)(b_ * N_HEADS + h_) * D_HEAD + dh) * S_LEN + s_] = f2bf(v);
                }
            }
        }
    }
}

__global__ __launch_bounds__(256) void qkv_kernel(
    const unsigned short* __restrict__ Xb, const unsigned short* __restrict__ Wb,
    const float* __restrict__ bq, const float* __restrict__ bk, const float* __restrict__ bv,
    unsigned short* Qh, unsigned short* Kh, unsigned short* Vt)
{
    const int z = blockIdx.z;
    const unsigned short* A = Xb + (size_t)z * 2097152;
    const unsigned short* W = Wb + (size_t)z * 1048576;
    const float* bias = (z == 0) ? bq : (z == 1) ? bk : bv;
    void* outp = (z == 0) ? (void*)Qh : (z == 1) ? (void*)Kh : (void*)Vt;
    gemm_core(A, W, bias, outp, (z == 2) ? 1 : 0, blockIdx.x * 128, blockIdx.y * 128);
}

__global__ __launch_bounds__(256) void oproj_kernel(
    const unsigned short* __restrict__ attn, const unsigned short* __restrict__ Wo,
    const float* __restrict__ bo, float* out)
{
    gemm_core(attn, Wo, bo, (void*)out, 2, blockIdx.x * 128, blockIdx.y * 128);
}

// ---------------- Attention stage A: S = exp(QK^T/8 + shift), masked ----------------
__global__ __launch_bounds__(256) void score_kernel(
    const unsigned short* __restrict__ Qh, const unsigned short* __restrict__ Kh,
    const int* __restrict__ mask, const float* __restrict__ shift,
    unsigned short* __restrict__ Sbuf, int bh0)
{
    __shared__ union {
        struct { unsigned short As[128 * 72]; unsigned short Bs[64 * 72]; } st;
        float C[128 * 68];
    } u;
    const int zloc = blockIdx.z;
    const int bh = bh0 + zloc;
    const int q0 = blockIdx.x * 128, j0 = blockIdx.y * 64;
    const int t = threadIdx.x, lane = t & 63, w = t >> 6;
    const int wm = w >> 1, wn = w & 1, g = lane >> 4, r = lane & 15;
    const unsigned short* Qb = Qh + (size_t)bh * S_LEN * D_HEAD;
    const unsigned short* Kb = Kh + (size_t)bh * S_LEN * D_HEAD;
    unsigned short* Sl = Sbuf + (size_t)zloc * S_LEN * S_LEN;
    const int* mrow = mask + (bh & (BATCH - 1)) * S_LEN;

    {
        int row = t >> 3, seg = t & 7;
#pragma unroll
        for (int i = 0; i < 4; ++i)
            *reinterpret_cast<short8*>(&u.st.As[(row + i * 32) * 72 + seg * 8]) =
                *reinterpret_cast<const short8*>(Qb + (size_t)(q0 + row + i * 32) * D_HEAD + seg * 8);
#pragma unroll
        for (int i = 0; i < 2; ++i)
            *reinterpret_cast<short8*>(&u.st.Bs[(row + i * 32) * 72 + seg * 8]) =
                *reinterpret_cast<const short8*>(Kb + (size_t)(j0 + row + i * 32) * D_HEAD + seg * 8);
    }
    __syncthreads();

    f32x4 acc[4][2];
#pragma unroll
    for (int mi = 0; mi < 4; ++mi)
#pragma unroll
        for (int ni = 0; ni < 2; ++ni)
            acc[mi][ni] = (f32x4){0.f, 0.f, 0.f, 0.f};

#pragma unroll
    for (int ks = 0; ks < 2; ++ks) {
        short8 af[4], bf[2];
#pragma unroll
        for (int mi = 0; mi < 4; ++mi)
            af[mi] = *reinterpret_cast<const short8*>(&u.st.As[(wm * 64 + mi * 16 + r) * 72 + ks * 32 + g * 8]);
#pragma unroll
        for (int ni = 0; ni < 2; ++ni)
            bf[ni] = *reinterpret_cast<const short8*>(&u.st.Bs[(wn * 32 + ni * 16 + r) * 72 + ks * 32 + g * 8]);
#pragma unroll
        for (int mi = 0; mi < 4; ++mi)
#pragma unroll
            for (int ni = 0; ni < 2; ++ni)
                acc[mi][ni] = __builtin_amdgcn_mfma_f32_16x16x32_bf16(af[mi], bf[ni], acc[mi][ni], 0, 0, 0);
    }
    __syncthreads();   // done with As/Bs; union becomes C

#pragma unroll
    for (int mi = 0; mi < 4; ++mi)
#pragma unroll
        for (int ni = 0; ni < 2; ++ni)
#pragma unroll
            for (int t4 = 0; t4 < 4; ++t4)
                u.C[(wm * 64 + mi * 16 + g * 4 + t4) * 68 + wn * 32 + ni * 16 + r] = acc[mi][ni][t4];
    __syncthreads();

#pragma unroll
    for (int c = 0; c < 8; ++c) {
        int flat = c * 1024 + t * 4;
        int row = flat >> 6;
        int col = flat & 63;
        f32x4 cv = *reinterpret_cast<const f32x4*>(&u.C[row * 68 + col]);
        f32x4 sv = *reinterpret_cast<const f32x4*>(
            shift + ((size_t)bh * S_LEN + q0 + row) * S_LEN + j0 + col);
        i32x4 mk = *reinterpret_cast<const i32x4*>(mrow + j0 + col);
        int mq = mrow[q0 + row];
        float p0 = (mq & mk[0]) ? __expf(fmaf(cv[0], 0.125f, sv[0])) : 0.f;
        float p1 = (mq & mk[1]) ? __expf(fmaf(cv[1], 0.125f, sv[1])) : 0.f;
        float p2 = (mq & mk[2]) ? __expf(fmaf(cv[2], 0.125f, sv[2])) : 0.f;
        float p3 = (mq & mk[3]) ? __expf(fmaf(cv[3], 0.125f, sv[3])) : 0.f;
        if (mq == 0) { p0 = p1 = p2 = p3 = 1.f; }
        ushort4 pk = { f2bf(p0), f2bf(p1), f2bf(p2), f2bf(p3) };
        *reinterpret_cast<ushort4*>(Sl + (size_t)(q0 + row) * S_LEN + j0 + col) = pk;
    }
}

// ---------------- Attention stage B: O = (S V) / rowsum(S), double-buffered ----------------
__global__ __launch_bounds__(256) void pv_kernel(
    const unsigned short* __restrict__ Sbuf, const unsigned short* __restrict__ Vt,
    unsigned short* __restrict__ attnbuf, int bh0)
{
    __shared__ unsigned short Ss[2][64 * 72];
    __shared__ unsigned short Vs[2][64 * 72];
    __shared__ float Lsum[64];
    const int zloc = blockIdx.y;
    const int bh = bh0 + zloc;
    const int q0 = blockIdx.x * 64;
    const int b_ = bh >> 4, h_ = bh & 15;
    const int t = threadIdx.x, lane = t & 63, w = t >> 6;
    const int wm = w >> 1, wn = w & 1, g = lane >> 4, r = lane & 15;
    const unsigned short* Sl = Sbuf + (size_t)zloc * S_LEN * S_LEN;
    const unsigned short* Vb = Vt + (size_t)bh * D_HEAD * S_LEN;
    const int srow = t >> 3, seg = t & 7;

    float rs0 = 0.f, rs1 = 0.f;
    f32x4 acc[2][2];
#pragma unroll
    for (int mi = 0; mi < 2; ++mi)
#pragma unroll
        for (int ni = 0; ni < 2; ++ni)
            acc[mi][ni] = (f32x4){0.f, 0.f, 0.f, 0.f};

    // prologue: stage kt=0 into buf 0
    {
        short8 sv0 = *reinterpret_cast<const short8*>(Sl + (size_t)(q0 + srow) * S_LEN + seg * 8);
        short8 sv1 = *reinterpret_cast<const short8*>(Sl + (size_t)(q0 + srow + 32) * S_LEN + seg * 8);
        short8 vv0 = *reinterpret_cast<const short8*>(Vb + (size_t)srow * S_LEN + seg * 8);
        short8 vv1 = *reinterpret_cast<const short8*>(Vb + (size_t)(srow + 32) * S_LEN + seg * 8);
        *reinterpret_cast<short8*>(&Ss[0][srow * 72 + seg * 8]) = sv0;
        *reinterpret_cast<short8*>(&Ss[0][(srow + 32) * 72 + seg * 8]) = sv1;
        *reinterpret_cast<short8*>(&Vs[0][srow * 72 + seg * 8]) = vv0;
        *reinterpret_cast<short8*>(&Vs[0][(srow + 32) * 72 + seg * 8]) = vv1;
        rs0 += sum8(sv0);
        rs1 += sum8(sv1);
    }
    __syncthreads();

    for (int kt = 0; kt < 16; ++kt) {
        const int cur = kt & 1;
        short8 sv0, sv1, vv0, vv1;
        if (kt < 15) {
            const int k0 = (kt + 1) * 64;
            sv0 = *reinterpret_cast<const short8*>(Sl + (size_t)(q0 + srow) * S_LEN + k0 + seg * 8);
            sv1 = *reinterpret_cast<const short8*>(Sl + (size_t)(q0 + srow + 32) * S_LEN + k0 + seg * 8);
            vv0 = *reinterpret_cast<const short8*>(Vb + (size_t)srow * S_LEN + k0 + seg * 8);
            vv1 = *reinterpret_cast<const short8*>(Vb + (size_t)(srow + 32) * S_LEN + k0 + seg * 8);
        }
#pragma unroll
        for (int ks = 0; ks < 2; ++ks) {
            short8 af[2], bf[2];
#pragma unroll
            for (int mi = 0; mi < 2; ++mi)
                af[mi] = *reinterpret_cast<const short8*>(&Ss[cur][(wm * 32 + mi * 16 + r) * 72 + ks * 32 + g * 8]);
#pragma unroll
            for (int ni = 0; ni < 2; ++ni)
                bf[ni] = *reinterpret_cast<const short8*>(&Vs[cur][(wn * 32 + ni * 16 + r) * 72 + ks * 32 + g * 8]);
#pragma unroll
            for (int mi = 0; mi < 2; ++mi)
#pragma unroll
                for (int ni = 0; ni < 2; ++ni)
                    acc[mi][ni] = __builtin_amdgcn_mfma_f32_16x16x32_bf16(af[mi], bf[ni], acc[mi][ni], 0, 0, 0);
        }
        if (kt < 15) {
            *reinterpret_cast<short8*>(&Ss[cur ^ 1][srow * 72 + seg * 8]) = sv0;
            *reinterpret_cast<short8*>(&Ss[cur ^ 1][(srow + 32) * 72 + seg * 8]) = sv1;
            *reinterpret_cast<short8*>(&Vs[cur ^ 1][srow * 72 + seg * 8]) = vv0;
            *reinterpret_cast<short8*>(&Vs[cur ^ 1][(srow + 32) * 72 + seg * 8]) = vv1;
            rs0 += sum8(sv0);
            rs1 += sum8(sv1);
        }
        __syncthreads();
    }

    rs0 += __shfl_xor(rs0, 1); rs0 += __shfl_xor(rs0, 2); rs0 += __shfl_xor(rs0, 4);
    rs1 += __shfl_xor(rs1, 1); rs1 += __shfl_xor(rs1, 2); rs1 += __shfl_xor(rs1, 4);
    if (seg == 0) { Lsum[srow] = rs0; Lsum[srow + 32] = rs1; }
    __syncthreads();

#pragma unroll
    for (int mi = 0; mi < 2; ++mi)
#pragma unroll
        for (int ni = 0; ni < 2; ++ni)
#pragma unroll
            for (int t4 = 0; t4 < 4; ++t4) {
                int row = wm * 32 + mi * 16 + g * 4 + t4;
                int col = wn * 32 + ni * 16 + r;
                float o = acc[mi][ni][t4] / Lsum[row];
                attnbuf[((size_t)(b_ * S_LEN + q0 + row)) * DMODEL + h_ * D_HEAD + col] = f2bf(o);
            }
}

extern "C" void kernel_launch(void* const* d_in, const int* in_sizes, int n_in,
                              void* d_out, int out_size, void* d_ws, size_t ws_size,
                              hipStream_t stream)
{
    const float* q     = (const float*)d_in[0];
    const float* k     = (const float*)d_in[1];
    const float* v     = (const float*)d_in[2];
    const int*   mask  = (const int*)d_in[3];
    const float* shift = (const float*)d_in[4];
    const float* wq    = (const float*)d_in[5];
    const float* bq    = (const float*)d_in[6];
    const float* wk    = (const float*)d_in[7];
    const float* bk    = (const float*)d_in[8];
    const float* wv    = (const float*)d_in[9];
    const float* bv    = (const float*)d_in[10];
    const float* wo    = (const float*)d_in[11];
    const float* bo    = (const float*)d_in[12];
    float* out = (float*)d_out;

    // ws: Qh 4 | Kh 4 | Vt 4 | attnbuf 4 | Wb 8 | Xb 12 | Sbuf CH*2  (MB)
    const size_t nhalf = (size_t)N_BH * S_LEN * D_HEAD;   // 2M elems
    unsigned short* Qh = (unsigned short*)d_ws;
    unsigned short* Kh = Qh + nhalf;
    unsigned short* Vt = Kh + nhalf;
    unsigned short* attnbuf = Vt + nhalf;
    unsigned short* Wb = attnbuf + (size_t)BATCH * S_LEN * DMODEL;
    unsigned short* Xb = Wb + (size_t)4 * 1048576;
    unsigned short* Sbuf = Xb + (size_t)3 * 2097152;

    const size_t base = 36u * 1024 * 1024;
    const size_t sbytes = (size_t)S_LEN * S_LEN * 2;   // 2MB per bh
    int CH = 1;
    if (ws_size > base) {
        size_t c = (ws_size - base) / sbytes;
        CH = (c >= 32) ? 32 : (c < 1 ? 1 : (int)c);
    }

    dim3 blk(256);
    cvt_kernel<<<dim3(2048, 7), blk, 0, stream>>>(wq, wk, wv, wo, q, k, v, Wb, Xb);
    qkv_kernel<<<dim3(16, 8, 3), blk, 0, stream>>>(Xb, Wb, bq, bk, bv, Qh, Kh, Vt);
    for (int bh0 = 0; bh0 < N_BH; bh0 += CH) {
        int c = (N_BH - bh0 < CH) ? (N_BH - bh0) : CH;
        score_kernel<<<dim3(8, 16, c), blk, 0, stream>>>(Qh, Kh, mask, shift, Sbuf, bh0);
        pv_kernel<<<dim3(16, c), blk, 0, stream>>>(Sbuf, Vt, attnbuf, bh0);
    }
    oproj_kernel<<<dim3(16, 8), blk, 0, stream>>>(attnbuf, Wb + (size_t)3 * 1048576, bo, out);
}